// Round 4
// baseline (117.906 us; speedup 1.0000x reference)
//
#include <hip/hip_runtime.h>
#include <hip/hip_bf16.h>

#define ENC 15
#define HID 128

typedef __attribute__((ext_vector_type(4))) float f32x4;
typedef __attribute__((ext_vector_type(8))) short s16x8;
typedef __attribute__((ext_vector_type(4))) short s16x4;

static __device__ __forceinline__ short f2bf(float v) {
    __hip_bfloat16 h = __float2bfloat16(v);
    return __builtin_bit_cast(short, h);
}

// ---- weight prep: fp32 -> bf16 (zero-padded) into workspace ----
// ws layout (bf16 elements):
//   W1b [128][32]  @ 0      (k padded 18->32)
//   W2b [128][128] @ 4096
//   W3b [16][128]  @ 20480  (rows padded 3->16)
__global__ void NSC_prep_kernel(const float* __restrict__ W1,
                                const float* __restrict__ W2,
                                const float* __restrict__ W3,
                                __hip_bfloat16* __restrict__ ws) {
    int t = blockIdx.x * 256 + threadIdx.x;
    if (t < 4096) {
        int row = t >> 5, k = t & 31;
        float v = (k < 18) ? W1[row * 18 + k] : 0.0f;
        ws[t] = __float2bfloat16(v);
    } else if (t < 20480) {
        ws[t] = __float2bfloat16(W2[t - 4096]);
    } else if (t < 22528) {
        int i = t - 20480;
        int row = i >> 7, k = i & 127;
        float v = (row < 3) ? W3[row * 128 + k] : 0.0f;
        ws[t] = __float2bfloat16(v);
    }
}

// Persistent single-wave blocks. Each wave:
//   - hoists its W2 MFMA A-fragments into registers ONCE (32 x s16x8 = 128 VGPR)
//   - loops over pixel-groups of 32 (gid = blk + it*GRID), doing the full MLP.
// GEMMs swapped: C[feature][pixel] = W[feature][k] * H^T[k][pixel].
// LDS per block (time-shared, 8.6 KB):
//   X phase : bf16 [32 px][32 k], row 64 B, swizzle  byte ^= (px&3)<<4 (in Hb region)
//   H phase : bf16 [32 px][128 f], row 256 B, swizzle byte ^= (px&7)<<4
//   pArr    : float [32][3]
#define GRID 2048
__global__ __launch_bounds__(64, 2)
void NSC_59133109732095_kernel(
    const float* __restrict__ points,
    const float* __restrict__ encodings,
    const float* __restrict__ b1,
    const float* __restrict__ b2,
    const float* __restrict__ b3,
    const int*   __restrict__ complexes,
    const __hip_bfloat16* __restrict__ ws,
    float* __restrict__ out0,
    float* __restrict__ out1,
    float* __restrict__ out2,
    int nGroups)                       // C*8
{
    __shared__ __align__(16) char smem[8192];
    __shared__ float pArr[32][3];
    char* Xb = smem;   // [32][64 B]
    char* Hb = smem;   // [32][256 B]

    const int blk = blockIdx.x;
    const int t   = threadIdx.x;
    const int g   = (t >> 4) & 3;     // k-group 0..3
    const int r16 = t & 15;

    const __hip_bfloat16* W1b = ws;
    const __hip_bfloat16* W2b = ws + 4096;
    const __hip_bfloat16* W3b = ws + 20480;

    // ---- hoisted, loop-invariant: W2 A-fragments (128 VGPR) ----
    s16x8 w2f[32];
    #pragma unroll
    for (int ks = 0; ks < 4; ++ks)
        #pragma unroll
        for (int m = 0; m < 8; ++m)
            w2f[ks * 8 + m] = *(const s16x8*)(W2b + (m * 16 + r16) * 128 + ks * 32 + g * 8);

    for (int gid = blk; gid < nGroups; gid += GRID) {
        const int c  = gid >> 3;
        const int qq = gid & 7;       // 32-px group within the complex

        __syncthreads();  // previous iter's Hb reads done before X overwrite

        // ---- phase 0: bilinear interp; lanes 0..31 own one pixel each ----
        if (t < 32) {
            const int px = qq * 32 + t;
            const int pi = px >> 4, pj = px & 15;
            const float ui = (float)pi * (1.0f / 15.0f);
            const float uj = (float)pj * (1.0f / 15.0f);
            const float w00 = (1.0f - ui) * (1.0f - uj), w01 = (1.0f - ui) * uj;
            const float w10 = ui * (1.0f - uj),          w11 = ui * uj;
            const int v0 = complexes[c * 4 + 0], v1 = complexes[c * 4 + 1];
            const int v2 = complexes[c * 4 + 2], v3 = complexes[c * 4 + 3];

            float p[3];
            #pragma unroll
            for (int f = 0; f < 3; ++f)
                p[f] = w00 * points[v0 * 3 + f] + w01 * points[v1 * 3 + f]
                     + w10 * points[v2 * 3 + f] + w11 * points[v3 * 3 + f];

            float Xf[18];
            #pragma unroll
            for (int k = 0; k < ENC; ++k)
                Xf[k] = w00 * encodings[v0 * ENC + k] + w01 * encodings[v1 * ENC + k]
                      + w10 * encodings[v2 * ENC + k] + w11 * encodings[v3 * ENC + k];
            #pragma unroll
            for (int f = 0; f < 3; ++f) Xf[ENC + f] = __sinf(p[f]);

            pArr[t][0] = p[0]; pArr[t][1] = p[1]; pArr[t][2] = p[2];

            #pragma unroll
            for (int ch = 0; ch < 4; ++ch) {
                s16x8 v;
                #pragma unroll
                for (int i = 0; i < 8; ++i) {
                    int k = ch * 8 + i;
                    v[i] = (k < 18) ? f2bf(Xf[k]) : (short)0;
                }
                *(s16x8*)(Xb + t * 64 + ((ch * 16) ^ ((t & 3) << 4))) = v;
            }
        }
        __syncthreads();   // X + pArr visible

        // ---- layer 1: [128 j] x [32 k], bias-initialized ----
        f32x4 acc[8][2];
        #pragma unroll
        for (int m = 0; m < 8; ++m) {
            f32x4 bv = *(const f32x4*)(b1 + m * 16 + g * 4);
            acc[m][0] = bv; acc[m][1] = bv;
        }
        {
            s16x8 bx[2];
            #pragma unroll
            for (int n = 0; n < 2; ++n) {
                int px = n * 16 + r16;
                bx[n] = *(const s16x8*)(Xb + px * 64 + ((g * 16) ^ ((px & 3) << 4)));
            }
            #pragma unroll
            for (int m = 0; m < 8; ++m) {
                s16x8 a = *(const s16x8*)(W1b + (m * 16 + r16) * 32 + g * 8);
                acc[m][0] = __builtin_amdgcn_mfma_f32_16x16x32_bf16(a, bx[0], acc[m][0], 0, 0, 0);
                acc[m][1] = __builtin_amdgcn_mfma_f32_16x16x32_bf16(a, bx[1], acc[m][1], 0, 0, 0);
            }
        }
        __syncthreads();   // X reads done -> region becomes H

        // h1 = sin(acc) -> bf16 -> H
        #pragma unroll
        for (int m = 0; m < 8; ++m)
            #pragma unroll
            for (int n = 0; n < 2; ++n) {
                s16x4 hv;
                #pragma unroll
                for (int r = 0; r < 4; ++r) hv[r] = f2bf(__sinf(acc[m][n][r]));
                int px = n * 16 + r16;
                *(s16x4*)(Hb + px * 256 + ((m * 32 + g * 8) ^ ((px & 7) << 4))) = hv;
            }
        __syncthreads();   // h1 visible

        // ---- layer 2: [128 j] x [128 k], W2 frags from registers ----
        #pragma unroll
        for (int m = 0; m < 8; ++m) {
            f32x4 bv = *(const f32x4*)(b2 + m * 16 + g * 4);
            acc[m][0] = bv; acc[m][1] = bv;
        }
        #pragma unroll
        for (int ks = 0; ks < 4; ++ks) {
            s16x8 hb[2];
            #pragma unroll
            for (int n = 0; n < 2; ++n) {
                int px = n * 16 + r16;
                hb[n] = *(const s16x8*)(Hb + px * 256 + ((ks * 64 + g * 16) ^ ((px & 7) << 4)));
            }
            #pragma unroll
            for (int m = 0; m < 8; ++m) {
                acc[m][0] = __builtin_amdgcn_mfma_f32_16x16x32_bf16(w2f[ks * 8 + m], hb[0], acc[m][0], 0, 0, 0);
                acc[m][1] = __builtin_amdgcn_mfma_f32_16x16x32_bf16(w2f[ks * 8 + m], hb[1], acc[m][1], 0, 0, 0);
            }
        }
        __syncthreads();   // h1 reads done

        // h2 = sin(acc) -> bf16 -> H (overwrites h1)
        #pragma unroll
        for (int m = 0; m < 8; ++m)
            #pragma unroll
            for (int n = 0; n < 2; ++n) {
                s16x4 hv;
                #pragma unroll
                for (int r = 0; r < 4; ++r) hv[r] = f2bf(__sinf(acc[m][n][r]));
                int px = n * 16 + r16;
                *(s16x4*)(Hb + px * 256 + ((m * 32 + g * 8) ^ ((px & 7) << 4))) = hv;
            }
        __syncthreads();   // h2 visible

        // ---- layer 3: [16 j (3 used)] x [128 k] ----
        f32x4 acc3[2];
        acc3[0] = f32x4{0.f, 0.f, 0.f, 0.f};
        acc3[1] = f32x4{0.f, 0.f, 0.f, 0.f};
        #pragma unroll
        for (int ks = 0; ks < 4; ++ks) {
            s16x8 a3 = *(const s16x8*)(W3b + r16 * 128 + ks * 32 + g * 8);
            #pragma unroll
            for (int n = 0; n < 2; ++n) {
                int px = n * 16 + r16;
                s16x8 hb = *(const s16x8*)(Hb + px * 256 + ((ks * 64 + g * 16) ^ ((px & 7) << 4)));
                acc3[n] = __builtin_amdgcn_mfma_f32_16x16x32_bf16(a3, hb, acc3[n], 0, 0, 0);
            }
        }

        // ---- epilogue: lanes with g==0 hold j=0..3 in regs (j<3 valid) ----
        if (g == 0) {
            const float b30 = b3[0], b31 = b3[1], b32 = b3[2];
            #pragma unroll
            for (int n = 0; n < 2; ++n) {
                int pxl = n * 16 + r16;
                float x0 = acc3[n][0] + b30;
                float x1 = acc3[n][1] + b31;
                float x2 = acc3[n][2] + b32;
                float p0 = pArr[pxl][0], p1 = pArr[pxl][1], p2 = pArr[pxl][2];
                const int base = (c * 256 + qq * 32 + pxl) * 3;
                out0[base + 0] = p0 + x0;
                out0[base + 1] = p1 + x1;
                out0[base + 2] = p2 + x2;
                out1[base + 0] = x0;
                out1[base + 1] = x1;
                out1[base + 2] = x2;
            }
        }
    }
    if (blk == 0 && t == 0) out2[0] = 1.0f;
}

extern "C" void kernel_launch(void* const* d_in, const int* in_sizes, int n_in,
                              void* d_out, int out_size, void* d_ws, size_t ws_size,
                              hipStream_t stream) {
    const float* points    = (const float*)d_in[0];
    const float* encodings = (const float*)d_in[1];
    const float* W1        = (const float*)d_in[2];
    const float* b1        = (const float*)d_in[3];
    const float* W2        = (const float*)d_in[4];
    const float* b2        = (const float*)d_in[5];
    const float* W3        = (const float*)d_in[6];
    const float* b3        = (const float*)d_in[7];
    const int*   complexes = (const int*)d_in[8];

    const int C  = in_sizes[8] / 4;          // 2048
    const int N3 = C * 256 * 3;              // 1,572,864

    float* out0 = (float*)d_out;
    float* out1 = out0 + N3;
    float* out2 = out1 + N3;

    __hip_bfloat16* ws = (__hip_bfloat16*)d_ws;  // needs 45056 B

    NSC_prep_kernel<<<88, 256, 0, stream>>>(W1, W2, W3, ws);
    NSC_59133109732095_kernel<<<GRID, 64, 0, stream>>>(
        points, encodings, b1, b2, b3, complexes, ws, out0, out1, out2, C * 8);
}

// Round 7
// 61.909 us; speedup vs baseline: 1.9045x; 1.9045x over previous
//
#include <hip/hip_runtime.h>
#include <hip/hip_bf16.h>

#define ENC 15
#define HID 128
#define RES 16

typedef __attribute__((ext_vector_type(4))) float f32x4;
typedef __attribute__((ext_vector_type(8))) short s16x8;
typedef __attribute__((ext_vector_type(4))) short s16x4;

static __device__ __forceinline__ short f2bf(float v) {
    __hip_bfloat16 h = __float2bfloat16(v);
    return __builtin_bit_cast(short, h);
}

// ---- weight prep: fp32 -> bf16 (zero-padded) into workspace ----
// ws layout (bf16 elements):
//   W1b [128][32]  @ 0      (k padded 18->32)
//   W2b [128][128] @ 4096
//   W3b [16][128]  @ 20480  (rows padded 3->16)
__global__ void NSC_prep_kernel(const float* __restrict__ W1,
                                const float* __restrict__ W2,
                                const float* __restrict__ W3,
                                __hip_bfloat16* __restrict__ ws) {
    int t = blockIdx.x * 256 + threadIdx.x;
    if (t < 4096) {
        int row = t >> 5, k = t & 31;
        float v = (k < 18) ? W1[row * 18 + k] : 0.0f;
        ws[t] = __float2bfloat16(v);
    } else if (t < 20480) {
        ws[t] = __float2bfloat16(W2[t - 4096]);
    } else if (t < 22528) {
        int i = t - 20480;
        int row = i >> 7, k = i & 127;
        float v = (row < 3) ? W3[row * 128 + k] : 0.0f;
        ws[t] = __float2bfloat16(v);
    }
}

// One block = one complex = 256 pixels (4 waves) — the PROVEN r2 structure.
// Surgical changes vs r2 only:
//   (1) X tile row stride 64 -> 80 B + wider XOR swizzle ((px^(px>>3))&3):
//       kills the 16-way bank conflict on phase-0 X writes (3.5M conflicts).
//   (2) Layer-2 A-fragments: batch all 8 loads per ks before the MFMAs
//       (8-deep load ILP instead of load->4xMFMA serial chains).
// All GEMMs swapped: C[feature][pixel] = W[feature][k] * H^T[k][pixel].
// LDS: one 64 KB buffer, time-shared:
//   X phase : bf16 [256 px][80 B rows], swizzle byte ^= ((px^(px>>3))&3)<<4
//   H phase : bf16 [256 px][128 f], row 256 B, swizzle byte ^= (px&7)<<4
//   outL    : float [256][5] at base (after H reads done)
__global__ __launch_bounds__(256, 2)
void NSC_59133109732095_kernel(
    const float* __restrict__ points,
    const float* __restrict__ encodings,
    const float* __restrict__ b1,
    const float* __restrict__ b2,
    const float* __restrict__ b3,
    const int*   __restrict__ complexes,
    const __hip_bfloat16* __restrict__ ws,
    float* __restrict__ out0,
    float* __restrict__ out1,
    float* __restrict__ out2)
{
    __shared__ __align__(16) char smem[65536];
    char*  Xb   = smem;           // [256][80 B]
    char*  Hb   = smem;           // [256][256 B]
    float* outL = (float*)smem;   // [256][5]

    const int c    = blockIdx.x;
    const int tid  = threadIdx.x;
    const int lane = tid & 63;
    const int wv   = tid >> 6;    // wave 0..3 -> pixels [wv*64, wv*64+64)
    const int g    = lane >> 4;   // k-group 0..3
    const int r16  = lane & 15;

    const __hip_bfloat16* W1b = ws;
    const __hip_bfloat16* W2b = ws + 4096;
    const __hip_bfloat16* W3b = ws + 20480;

    // ---- phase 0: per-thread bilinear interp, pixel = tid ----
    const int pi = tid >> 4, pj = tid & 15;
    const float ui = (float)pi * (1.0f / 15.0f);
    const float uj = (float)pj * (1.0f / 15.0f);
    const float w00 = (1.0f - ui) * (1.0f - uj), w01 = (1.0f - ui) * uj;
    const float w10 = ui * (1.0f - uj),          w11 = ui * uj;
    const int v0 = complexes[c * 4 + 0], v1 = complexes[c * 4 + 1];
    const int v2 = complexes[c * 4 + 2], v3 = complexes[c * 4 + 3];

    float p[3];
    #pragma unroll
    for (int f = 0; f < 3; ++f)
        p[f] = w00 * points[v0 * 3 + f] + w01 * points[v1 * 3 + f]
             + w10 * points[v2 * 3 + f] + w11 * points[v3 * 3 + f];

    float Xf[18];
    #pragma unroll
    for (int k = 0; k < ENC; ++k)
        Xf[k] = w00 * encodings[v0 * ENC + k] + w01 * encodings[v1 * ENC + k]
              + w10 * encodings[v2 * ENC + k] + w11 * encodings[v3 * ENC + k];
    #pragma unroll
    for (int f = 0; f < 3; ++f) Xf[ENC + f] = __sinf(p[f]);

    // write X row (32 bf16, zero-padded), stride 80, conflict-free swizzle
    #pragma unroll
    for (int t = 0; t < 4; ++t) {
        s16x8 v;
        #pragma unroll
        for (int i = 0; i < 8; ++i) {
            int k = t * 8 + i;
            v[i] = (k < 18) ? f2bf(Xf[k]) : (short)0;
        }
        *(s16x8*)(Xb + tid * 80 + ((t * 16) ^ (((tid ^ (tid >> 3)) & 3) << 4))) = v;
    }
    __syncthreads();   // A: X visible

    // ---- layer 1: [128 j] x [32 k] -> acc[j][px], bias-initialized ----
    f32x4 acc[8][4];
    #pragma unroll
    for (int m = 0; m < 8; ++m) {
        f32x4 bv = *(const f32x4*)(b1 + m * 16 + g * 4);
        #pragma unroll
        for (int n = 0; n < 4; ++n) acc[m][n] = bv;
    }
    {
        s16x8 a1[8];
        #pragma unroll
        for (int m = 0; m < 8; ++m)
            a1[m] = *(const s16x8*)(W1b + (m * 16 + r16) * 32 + g * 8);
        s16x8 bx[4];
        #pragma unroll
        for (int n = 0; n < 4; ++n) {
            int px = wv * 64 + n * 16 + r16;
            bx[n] = *(const s16x8*)(Xb + px * 80 + ((g * 16) ^ (((px ^ (px >> 3)) & 3) << 4)));
        }
        #pragma unroll
        for (int m = 0; m < 8; ++m)
            #pragma unroll
            for (int n = 0; n < 4; ++n)
                acc[m][n] = __builtin_amdgcn_mfma_f32_16x16x32_bf16(a1[m], bx[n], acc[m][n], 0, 0, 0);
    }
    __syncthreads();   // B: X reads done, region may become H

    // sin -> bf16 -> H (h1), packed b64 per tile
    #pragma unroll
    for (int m = 0; m < 8; ++m)
        #pragma unroll
        for (int n = 0; n < 4; ++n) {
            s16x4 hv;
            #pragma unroll
            for (int r = 0; r < 4; ++r) hv[r] = f2bf(__sinf(acc[m][n][r]));
            int px = wv * 64 + n * 16 + r16;
            *(s16x4*)(Hb + px * 256 + ((m * 32 + g * 8) ^ ((px & 7) << 4))) = hv;
        }
    __syncthreads();   // C: h1 visible

    // ---- layer 2: [128 j] x [128 k], batched A-loads per ks ----
    #pragma unroll
    for (int m = 0; m < 8; ++m) {
        f32x4 bv = *(const f32x4*)(b2 + m * 16 + g * 4);
        #pragma unroll
        for (int n = 0; n < 4; ++n) acc[m][n] = bv;
    }
    #pragma unroll
    for (int ks = 0; ks < 4; ++ks) {
        s16x8 hb[4];
        #pragma unroll
        for (int n = 0; n < 4; ++n) {
            int px = wv * 64 + n * 16 + r16;
            hb[n] = *(const s16x8*)(Hb + px * 256 + ((ks * 64 + g * 16) ^ ((px & 7) << 4)));
        }
        s16x8 a2[8];
        #pragma unroll
        for (int m = 0; m < 8; ++m)
            a2[m] = *(const s16x8*)(W2b + (m * 16 + r16) * 128 + ks * 32 + g * 8);
        #pragma unroll
        for (int m = 0; m < 8; ++m)
            #pragma unroll
            for (int n = 0; n < 4; ++n)
                acc[m][n] = __builtin_amdgcn_mfma_f32_16x16x32_bf16(a2[m], hb[n], acc[m][n], 0, 0, 0);
    }
    __syncthreads();   // D: h1 reads done

    // sin -> bf16 -> H (h2 overwrites h1)
    #pragma unroll
    for (int m = 0; m < 8; ++m)
        #pragma unroll
        for (int n = 0; n < 4; ++n) {
            s16x4 hv;
            #pragma unroll
            for (int r = 0; r < 4; ++r) hv[r] = f2bf(__sinf(acc[m][n][r]));
            int px = wv * 64 + n * 16 + r16;
            *(s16x4*)(Hb + px * 256 + ((m * 32 + g * 8) ^ ((px & 7) << 4))) = hv;
        }
    __syncthreads();   // E: h2 visible

    // ---- layer 3: [16 j (3 used)] x [128 k] ----
    f32x4 acc3[4];
    #pragma unroll
    for (int n = 0; n < 4; ++n) acc3[n] = f32x4{0.f, 0.f, 0.f, 0.f};
    #pragma unroll
    for (int ks = 0; ks < 4; ++ks) {
        s16x8 a3 = *(const s16x8*)(W3b + r16 * 128 + ks * 32 + g * 8);
        #pragma unroll
        for (int n = 0; n < 4; ++n) {
            int px = wv * 64 + n * 16 + r16;
            s16x8 hb = *(const s16x8*)(Hb + px * 256 + ((ks * 64 + g * 16) ^ ((px & 7) << 4)));
            acc3[n] = __builtin_amdgcn_mfma_f32_16x16x32_bf16(a3, hb, acc3[n], 0, 0, 0);
        }
    }
    __syncthreads();   // F: h2 reads done, region may become outL

    if (g == 0) {      // lanes holding j = 0..3 (regs), j<3 valid
        #pragma unroll
        for (int n = 0; n < 4; ++n) {
            int px = wv * 64 + n * 16 + r16;
            outL[px * 5 + 0] = acc3[n][0];
            outL[px * 5 + 1] = acc3[n][1];
            outL[px * 5 + 2] = acc3[n][2];
        }
    }
    __syncthreads();   // G: outL visible

    // ---- epilogue: thread tid owns pixel tid ----
    float x0 = outL[tid * 5 + 0] + b3[0];
    float x1 = outL[tid * 5 + 1] + b3[1];
    float x2 = outL[tid * 5 + 2] + b3[2];
    const int base = c * 768 + tid * 3;
    out0[base + 0] = p[0] + x0;
    out0[base + 1] = p[1] + x1;
    out0[base + 2] = p[2] + x2;
    out1[base + 0] = x0;
    out1[base + 1] = x1;
    out1[base + 2] = x2;
    if (c == 0 && tid == 0) out2[0] = 1.0f;
}

extern "C" void kernel_launch(void* const* d_in, const int* in_sizes, int n_in,
                              void* d_out, int out_size, void* d_ws, size_t ws_size,
                              hipStream_t stream) {
    const float* points    = (const float*)d_in[0];
    const float* encodings = (const float*)d_in[1];
    const float* W1        = (const float*)d_in[2];
    const float* b1        = (const float*)d_in[3];
    const float* W2        = (const float*)d_in[4];
    const float* b2        = (const float*)d_in[5];
    const float* W3        = (const float*)d_in[6];
    const float* b3        = (const float*)d_in[7];
    const int*   complexes = (const int*)d_in[8];

    const int C  = in_sizes[8] / 4;          // 2048
    const int N3 = C * RES * RES * 3;        // 1,572,864

    float* out0 = (float*)d_out;
    float* out1 = out0 + N3;
    float* out2 = out1 + N3;

    __hip_bfloat16* ws = (__hip_bfloat16*)d_ws;  // needs 45056 B

    NSC_prep_kernel<<<88, 256, 0, stream>>>(W1, W2, W3, ws);
    NSC_59133109732095_kernel<<<C, 256, 0, stream>>>(
        points, encodings, b1, b2, b3, complexes, ws, out0, out1, out2);
}